// Round 1
// baseline (11900.894 us; speedup 1.0000x reference)
//
#include <hip/hip_runtime.h>
#include <math.h>

#define H_IN   48
#define W_IN   48
#define H_OUTC 192
#define W_OUTC 192
#define INC    32
#define OUTC   3
#define KS     4
#define FT     16
#define LINI   20
#define Dn     1536
#define D8n    192
#define D4n    384
#define D2n    768
#define PIX    16

__device__ __forceinline__ int reflect48(int i) {
    return (i < 0) ? -i : ((i > 47) ? 94 - i : i);
}

// ---------------- feature_trans conv: lr[2,32,48,48] -> ftmap[2,16,48,48] ----------------
__global__ __launch_bounds__(256) void ft_kernel(const float* __restrict__ lr,
                                                 const float* __restrict__ ft_w,
                                                 const float* __restrict__ ft_b,
                                                 float* __restrict__ ftmap) {
    int idx = blockIdx.x * 256 + threadIdx.x;        // ((b*16+o)*48+y)*48+x
    if (idx >= 2 * FT * H_IN * W_IN) return;
    int x = idx % W_IN;
    int y = (idx / W_IN) % H_IN;
    int o = (idx / (W_IN * H_IN)) % FT;
    int bb = idx / (W_IN * H_IN * FT);
    float acc = ft_b[o];
    for (int c = 0; c < INC; ++c) {
        const float* lrc = lr + ((bb * INC + c) * H_IN) * W_IN;
        const float* wc  = ft_w + ((o * INC + c) * KS) * KS;
        #pragma unroll
        for (int dy = 0; dy < 4; ++dy) {
            int ry = reflect48(y + dy - 1);
            #pragma unroll
            for (int dx = 0; dx < 4; ++dx) {
                int rx = reflect48(x + dx - 1);
                acc += lrc[ry * W_IN + rx] * wc[dy * 4 + dx];
            }
        }
    }
    ftmap[idx] = acc;
}

// 16 FMAs: ACC[p] += row[p] * WV, row read as 4x float4 (broadcast across lanes)
#define FMA16(ACC, SRCROW, WV) do {                                           \
    const float4* _v = (const float4*)(SRCROW);                               \
    float4 _a0 = _v[0], _a1 = _v[1], _a2 = _v[2], _a3 = _v[3];                \
    ACC[0]  += _a0.x*(WV); ACC[1]  += _a0.y*(WV); ACC[2]  += _a0.z*(WV); ACC[3]  += _a0.w*(WV); \
    ACC[4]  += _a1.x*(WV); ACC[5]  += _a1.y*(WV); ACC[6]  += _a1.z*(WV); ACC[7]  += _a1.w*(WV); \
    ACC[8]  += _a2.x*(WV); ACC[9]  += _a2.y*(WV); ACC[10] += _a2.z*(WV); ACC[11] += _a2.w*(WV); \
    ACC[12] += _a3.x*(WV); ACC[13] += _a3.y*(WV); ACC[14] += _a3.z*(WV); ACC[15] += _a3.w*(WV); \
} while (0)

// ---------------- fused per-pixel MLP + slice_mul ----------------
// block = 256 threads, PIX=16 consecutive pixels of one output row
__global__ __launch_bounds__(256, 2) void fused_kernel(
    const float* __restrict__ lr, const float* __restrict__ ftmap,
    const float* __restrict__ l1w1, const float* __restrict__ l1b1,
    const float* __restrict__ l1w2, const float* __restrict__ l1b2,
    const float* __restrict__ l2w1, const float* __restrict__ l2b1,
    const float* __restrict__ l2w2, const float* __restrict__ l2b2,
    const float* __restrict__ l3w1, const float* __restrict__ l3b1,
    const float* __restrict__ l3w2, const float* __restrict__ l3b2,
    float* __restrict__ out)
{
    __shared__ __align__(16) char U[49152];          // unioned buffers
    __shared__ float s_osf[PIX][LINI];
    __shared__ int   s_fw[PIX];
    __shared__ float red[4][48];

    float (*h1T)[PIX] = (float (*)[PIX])(U);                 // [192][16]
    float (*h2T)[PIX] = (float (*)[PIX])(U + 12288);         // [192][16]
    float (*f1T)[PIX] = (float (*)[PIX])(U + 24576);         // [192][16]
    float (*f2T)[PIX] = (float (*)[PIX])(U + 36864);         // [192][16]
    float (*fT)[PIX]  = (float (*)[PIX])(U);                 // [384][16] (over h1,h2)
    float (*gT)[PIX]  = (float (*)[PIX])(U + 24576);         // [256][16] (over f1,f2)

    const int tid = threadIdx.x;
    const int bid = blockIdx.x;
    const int bpr = W_OUTC / PIX;                    // 12 blocks per row
    const int b   = bid / (H_OUTC * bpr);
    int rem       = bid % (H_OUTC * bpr);
    const int h   = rem / bpr;
    const int w0  = (rem % bpr) * PIX;

    const float ch = (h + 1) * 0.25f - 0.625f;
    const int   fh = (int)floorf(ch);
    const float offh = (float)fh - ch;
    const int   rfh = reflect48(fh);

    if (tid < PIX) {
        int w = w0 + tid;
        float cw = (w + 1) * 0.25f - 0.625f;
        int fw = (int)floorf(cw);
        s_fw[tid] = fw;
        s_osf[tid][16] = offh;
        s_osf[tid][17] = (float)fw - cw;
        s_osf[tid][18] = 4.0f;
        s_osf[tid][19] = 4.0f;
    }
    __syncthreads();
    {   // srf: 16 pixels x 16 ft channels = 256
        int p = tid / FT, cch = tid % FT;
        int rfw = reflect48(s_fw[p]);
        s_osf[p][cch] = ftmap[((b * FT + cch) * H_IN + rfh) * W_IN + rfw];
    }
    __syncthreads();

    // ---- phase 1a: h{1,2} = tanh(osf @ l{1,2}w1 + b)  -> h1T/h2T [192][16]
    for (int idx = tid; idx < 2 * PIX * D8n; idx += 256) {
        int br = idx / (PIX * D8n);
        int r  = idx % (PIX * D8n);
        int p  = r / D8n;
        int j  = r % D8n;
        const float* W = br ? l2w1 : l1w1;
        const float* B = br ? l2b1 : l1b1;
        float acc = B[j];
        #pragma unroll
        for (int i = 0; i < LINI; ++i)
            acc += s_osf[p][i] * W[i * D8n + j];
        (br ? h2T : h1T)[j][p] = tanhf(acc);
    }
    __syncthreads();

    // ---- phase 1b: f{1,2} = h{1,2} @ l{1,2}w2 + b  -> f1T/f2T [192][16]
    for (int cidx = tid; cidx < 2 * D8n; cidx += 256) {
        int br = cidx / D8n;
        int j  = cidx % D8n;
        const float* W = br ? l2w2 : l1w2;
        const float* B = br ? l2b2 : l1b2;
        float (*hT)[PIX]  = br ? h2T : h1T;
        float (*fTd)[PIX] = br ? f2T : f1T;
        float acc[PIX];
        #pragma unroll
        for (int p = 0; p < PIX; ++p) acc[p] = 0.f;
        for (int i = 0; i < D8n; ++i) {
            float wv = W[i * D8n + j];
            FMA16(acc, &hT[i][0], wv);
        }
        float bj = B[j];
        #pragma unroll
        for (int p = 0; p < PIX; ++p) fTd[j][p] = acc[p] + bj;
    }
    __syncthreads();

    // ---- phase 1c: f = tanh([f1*f2, f1]) -> fT [384][16]
    for (int idx = tid; idx < PIX * D4n; idx += 256) {
        int j = idx / PIX;
        int p = idx % PIX;
        float v = (j < D8n) ? tanhf(f1T[j][p] * f2T[j][p]) : tanhf(f1T[j - D8n][p]);
        fT[j][p] = v;
    }
    __syncthreads();

    // ---- phase 2+3: g = leaky(f @ l3w1 + b), chunked; out += (g @ l3w2 + b) .* sel
    float accA[PIX], accB[PIX], accC[PIX];
    #pragma unroll
    for (int p = 0; p < PIX; ++p) { accA[p] = 0.f; accB[p] = 0.f; accC[p] = 0.f; }

    for (int cc = 0; cc < 3; ++cc) {
        {   // g chunk: column jg = cc*256 + tid
            int jg = cc * 256 + tid;
            float acc[PIX];
            #pragma unroll
            for (int p = 0; p < PIX; ++p) acc[p] = 0.f;
            for (int i = 0; i < D4n; ++i) {
                float wv = l3w1[i * D2n + jg];
                FMA16(acc, &fT[i][0], wv);
            }
            float bj = l3b1[jg];
            #pragma unroll
            for (int p = 0; p < PIX; ++p) {
                float gv = acc[p] + bj;
                gT[tid][p] = (gv > 0.f) ? gv : 0.01f * gv;
            }
        }
        __syncthreads();
        // accumulate: each thread owns 6 n-columns
        for (int m = 0; m < 6; ++m) {
            int n  = tid + (m << 8);
            int oc = n >> 9;
            int k  = n & 511;
            int c  = k >> 4, k1 = (k >> 2) & 3, k2 = k & 3;
            int row = reflect48(fh - 1 + k1);
            const float* lrrow = lr + ((b * INC + c) * H_IN + row) * W_IN;
            const float* Wcol  = l3w2 + (size_t)(cc * 256) * Dn + n;
            float wpart[PIX];
            #pragma unroll
            for (int p = 0; p < PIX; ++p) wpart[p] = 0.f;
            for (int j = 0; j < 256; ++j) {
                float wv = Wcol[(size_t)j * Dn];
                FMA16(wpart, &gT[j][0], wv);
            }
            float bn = (cc == 0) ? l3b2[n] : 0.f;
            #pragma unroll
            for (int p = 0; p < PIX; ++p) {
                float sv = lrrow[reflect48(s_fw[p] - 1 + k2)];
                float val = (wpart[p] + bn) * sv;
                if (oc == 0)      accA[p] += val;
                else if (oc == 1) accB[p] += val;
                else              accC[p] += val;
            }
        }
        __syncthreads();
    }

    // ---- reduction over 256 threads -> out
    const int lane = tid & 63;
    const int wid  = tid >> 6;
    #pragma unroll
    for (int p = 0; p < PIX; ++p) {
        float a = accA[p], bv = accB[p], cv = accC[p];
        #pragma unroll
        for (int off = 32; off > 0; off >>= 1) {
            a  += __shfl_down(a, off);
            bv += __shfl_down(bv, off);
            cv += __shfl_down(cv, off);
        }
        if (lane == 0) { red[wid][p * 3 + 0] = a; red[wid][p * 3 + 1] = bv; red[wid][p * 3 + 2] = cv; }
    }
    __syncthreads();
    if (tid < 48) {
        float s = red[0][tid] + red[1][tid] + red[2][tid] + red[3][tid];
        int p = tid / 3, oc = tid % 3;
        out[((b * OUTC + oc) * H_OUTC + h) * W_OUTC + (w0 + p)] = tanhf(s);
    }
}

extern "C" void kernel_launch(void* const* d_in, const int* in_sizes, int n_in,
                              void* d_out, int out_size, void* d_ws, size_t ws_size,
                              hipStream_t stream) {
    const float* lr   = (const float*)d_in[0];
    // d_in[1] = kernel_pc (unused by reference); d_in[2]/d_in[3] = h_out/w_out (static 192)
    const float* ft_w = (const float*)d_in[4];
    const float* ft_b = (const float*)d_in[5];
    const float* l1w1 = (const float*)d_in[6];
    const float* l1b1 = (const float*)d_in[7];
    const float* l1w2 = (const float*)d_in[8];
    const float* l1b2 = (const float*)d_in[9];
    const float* l2w1 = (const float*)d_in[10];
    const float* l2b1 = (const float*)d_in[11];
    const float* l2w2 = (const float*)d_in[12];
    const float* l2b2 = (const float*)d_in[13];
    const float* l3w1 = (const float*)d_in[14];
    const float* l3b1 = (const float*)d_in[15];
    const float* l3w2 = (const float*)d_in[16];
    const float* l3b2 = (const float*)d_in[17];
    float* outp  = (float*)d_out;
    float* ftmap = (float*)d_ws;                    // 2*16*48*48 floats = 294912 B

    hipLaunchKernelGGL(ft_kernel, dim3(288), dim3(256), 0, stream, lr, ft_w, ft_b, ftmap);

    const int nblocks = 2 * H_OUTC * (W_OUTC / PIX);  // 4608
    hipLaunchKernelGGL(fused_kernel, dim3(nblocks), dim3(256), 0, stream,
                       lr, ftmap,
                       l1w1, l1b1, l1w2, l1b2,
                       l2w1, l2b1, l2w2, l2b2,
                       l3w1, l3b1, l3w2, l3b2,
                       outp);
}

// Round 2
// 868.734 us; speedup vs baseline: 13.6991x; 13.6991x over previous
//
#include <hip/hip_runtime.h>
#include <math.h>

#define H_IN   48
#define W_IN   48
#define INC    32
#define OUTC   3
#define FT     16
#define Dn     1536
#define D8n    192
#define D4n    384
#define D2n    768
#define PIX    32

typedef _Float16 h16;
typedef _Float16 f16x8 __attribute__((ext_vector_type(8)));
typedef float    f32x4 __attribute__((ext_vector_type(4)));

#define MFMA16(a, b, c) __builtin_amdgcn_mfma_f32_16x16x32_f16((a), (b), (c), 0, 0, 0)

// ---- LDS layout (bytes), total 63104 < 64KB ----
#define OFF_G    0        // g  [32] rows x 1536B (f16 [32][768])   phase4w/5r
#define OFF_H1   0        // h1 [32] rows x 384B                    phase1w/2r
#define OFF_H2   12288    // h2
#define OFF_OSF  24576    // osf f32 [32][20]                       phase0w/1r
#define OFF_F    0        // f  [32] rows x 768B (f16 [32][384])    phase2w/4r
#define OFF_LR   49152    // lrrows f16 [32][4][48] = 12288B
#define OFF_SC   61440    // selcol u8 [32][4] = 128B
#define OFF_RED  61568    // red f32 [4][32][3] = 1536B
#define S_BYTES  63104

__device__ __forceinline__ int reflect48(int i) {
    return (i < 0) ? -i : ((i > 47) ? 94 - i : i);
}

__device__ __forceinline__ float tanhf_fast(float x) {
    float e = __expf(2.f * x);
    return 1.f - 2.f / (e + 1.f);
}

// row-XOR swizzle: byte column ^ ((row&7)<<4); valid for row sizes 384/768/1536
#define SWZ(p, bc) ((bc) ^ (((p) & 7) << 4))

// ---------------- feature_trans conv ----------------
__global__ __launch_bounds__(256) void ft_kernel(const float* __restrict__ lr,
                                                 const float* __restrict__ ft_w,
                                                 const float* __restrict__ ft_b,
                                                 float* __restrict__ ftmap) {
    int idx = blockIdx.x * 256 + threadIdx.x;
    if (idx >= 2 * FT * H_IN * W_IN) return;
    int x = idx % W_IN;
    int y = (idx / W_IN) % H_IN;
    int o = (idx / (W_IN * H_IN)) % FT;
    int bb = idx / (W_IN * H_IN * FT);
    float acc = ft_b[o];
    for (int c = 0; c < INC; ++c) {
        const float* lrc = lr + ((bb * INC + c) * H_IN) * W_IN;
        const float* wc  = ft_w + ((o * INC + c) * 4) * 4;
        #pragma unroll
        for (int dy = 0; dy < 4; ++dy) {
            int ry = reflect48(y + dy - 1);
            #pragma unroll
            for (int dx = 0; dx < 4; ++dx) {
                int rx = reflect48(x + dx - 1);
                acc += lrc[ry * W_IN + rx] * wc[dy * 4 + dx];
            }
        }
    }
    ftmap[idx] = acc;
}

// ---------------- weight transpose + f32->f16 ----------------
__global__ __launch_bounds__(256) void prep_kernel(const float* __restrict__ l1w2,
                                                   const float* __restrict__ l2w2,
                                                   const float* __restrict__ l3w1,
                                                   const float* __restrict__ l3w2,
                                                   h16* __restrict__ w12t, h16* __restrict__ w22t,
                                                   h16* __restrict__ w31t, h16* __restrict__ w32t) {
    __shared__ float tile[32][33];
    int bid = blockIdx.x;
    const float* src; h16* dst; int K, N, t0;
    if (bid < 36)      { src = l1w2; dst = w12t; K = 192; N = 192;  t0 = 0; }
    else if (bid < 72) { src = l2w2; dst = w22t; K = 192; N = 192;  t0 = 36; }
    else if (bid < 360){ src = l3w1; dst = w31t; K = 384; N = 768;  t0 = 72; }
    else               { src = l3w2; dst = w32t; K = 768; N = 1536; t0 = 360; }
    int t = bid - t0;
    int ntx = N >> 5;
    int kt = t / ntx, nt = t - kt * ntx;
    int k0 = kt << 5, n0 = nt << 5;
    int tx = threadIdx.x & 31, ty = threadIdx.x >> 5;
    #pragma unroll
    for (int i = 0; i < 4; ++i)
        tile[ty + i * 8][tx] = src[(k0 + ty + i * 8) * N + n0 + tx];
    __syncthreads();
    #pragma unroll
    for (int i = 0; i < 4; ++i)
        dst[(n0 + ty + i * 8) * K + k0 + tx] = (h16)tile[tx][ty + i * 8];
}

// ---------------- fused MFMA kernel: 32 pixels/block ----------------
__global__ __launch_bounds__(256, 2) void fused_kernel(
    const float* __restrict__ lr, const float* __restrict__ ftmap,
    const float* __restrict__ l1w1, const float* __restrict__ l1b1,
    const float* __restrict__ l2w1, const float* __restrict__ l2b1,
    const float* __restrict__ l1b2, const float* __restrict__ l2b2,
    const float* __restrict__ l3b1, const float* __restrict__ l3b2,
    const h16* __restrict__ W12T, const h16* __restrict__ W22T,
    const h16* __restrict__ W31T, const h16* __restrict__ W32T,
    float* __restrict__ out)
{
    __shared__ __align__(16) char S[S_BYTES];

    const int tid  = threadIdx.x;
    const int lane = tid & 63;
    const int wv   = tid >> 6;         // wave 0..3
    const int bid  = blockIdx.x;
    const int b    = bid / 1152;       // 192 rows * 6 blocks/row
    const int rem  = bid % 1152;
    const int h    = rem / 6;
    const int w0   = (rem % 6) * PIX;

    const float ch = (h + 1) * 0.25f - 0.625f;
    const int   fh = (int)floorf(ch);
    const float offh = (float)fh - ch;
    const int   rfh = reflect48(fh);

    float* s_osf = (float*)(S + OFF_OSF);
    unsigned char* s_sc = (unsigned char*)(S + OFF_SC);
    h16*   s_lrr = (h16*)(S + OFF_LR);
    float* s_red = (float*)(S + OFF_RED);

    // ---------- phase 0: osf / selcol / lrrows / red ----------
    if (tid < 128) {
        int p = tid >> 2, k2 = tid & 3;
        int w = w0 + p;
        float cw = (w + 1) * 0.25f - 0.625f;
        int fw = (int)floorf(cw);
        s_sc[p * 4 + k2] = (unsigned char)reflect48(fw - 1 + k2);
        if (k2 == 0) {
            float* o = s_osf + p * 20;
            o[16] = offh; o[17] = (float)fw - cw; o[18] = 4.f; o[19] = 4.f;
        }
    }
    {   // srf gather: 32p x 16ch
        int p = tid >> 3;
        int c0 = (tid & 7) * 2;
        int w = w0 + p;
        float cw = (w + 1) * 0.25f - 0.625f;
        int rfw = reflect48((int)floorf(cw));
        float* o = s_osf + p * 20;
        o[c0]     = ftmap[((b * FT + c0) * H_IN + rfh) * W_IN + rfw];
        o[c0 + 1] = ftmap[((b * FT + c0 + 1) * H_IN + rfh) * W_IN + rfw];
    }
    for (int idx = tid; idx < 32 * 4 * 48; idx += 256) {
        int c = idx / 192, r2 = idx - c * 192, k1 = r2 / 48, col = r2 - k1 * 48;
        int row = reflect48(fh - 1 + k1);
        s_lrr[idx] = (h16)lr[((b * INC + c) * H_IN + row) * W_IN + col];
    }
    for (int idx = tid; idx < 4 * 32 * 3; idx += 256) s_red[idx] = 0.f;
    __syncthreads();

    // ---------- phase 1: h{1,2} = tanh(osf @ l{1,2}w1 + b) -> LDS f16 ----------
    for (int idx = tid; idx < 2 * 32 * D8n; idx += 256) {
        int br = idx / 6144;
        int r2 = idx - br * 6144;
        int p  = r2 / D8n;
        int j  = r2 - p * D8n;
        const float* W = br ? l2w1 : l1w1;
        const float* B = br ? l2b1 : l1b1;
        const float* o = s_osf + p * 20;
        float acc = B[j];
        #pragma unroll
        for (int i = 0; i < 20; ++i) acc += o[i] * W[i * D8n + j];
        int base = br ? OFF_H2 : OFF_H1;
        *(h16*)(S + base + p * 384 + SWZ(p, j * 2)) = (h16)tanhf_fast(acc);
    }
    __syncthreads();

    // ---------- phase 2 A-load: h fragments -> regs ----------
    f16x8 Ah[2][2][6];                 // [branch][rowtile][kf]
    {
        int pr = lane & 15, kg = (lane >> 4) << 3;
        #pragma unroll
        for (int br = 0; br < 2; ++br)
            #pragma unroll
            for (int rt = 0; rt < 2; ++rt) {
                int p = rt * 16 + pr;
                #pragma unroll
                for (int kf = 0; kf < 6; ++kf) {
                    int k0 = kf * 32 + kg;
                    Ah[br][rt][kf] = *(const f16x8*)(S + (br ? OFF_H2 : OFF_H1) + p * 384 + SWZ(p, k0 * 2));
                }
            }
    }
    __syncthreads();   // h dead; f region (aliases h) may now be written

    // ---------- phase 2 compute + merge -> f LDS f16 ----------
    {
        int pr = lane & 15, kg = (lane >> 4) << 3;
        #pragma unroll
        for (int cc = 0; cc < 3; ++cc) {
            int c = wv * 3 + cc;
            int n = c * 16 + pr;
            f32x4 a00 = {0.f,0.f,0.f,0.f}, a01 = a00, a10 = a00, a11 = a00;
            #pragma unroll
            for (int kf = 0; kf < 6; ++kf) {
                int koff = kf * 32 + kg;
                f16x8 b0 = *(const f16x8*)(W12T + n * D8n + koff);
                f16x8 b1 = *(const f16x8*)(W22T + n * D8n + koff);
                a00 = MFMA16(Ah[0][0][kf], b0, a00);
                a01 = MFMA16(Ah[0][1][kf], b0, a01);
                a10 = MFMA16(Ah[1][0][kf], b1, a10);
                a11 = MFMA16(Ah[1][1][kf], b1, a11);
            }
            float bf1 = l1b2[n], bf2 = l2b2[n];
            #pragma unroll
            for (int rt = 0; rt < 2; ++rt) {
                #pragma unroll
                for (int r = 0; r < 4; ++r) {
                    int p = rt * 16 + ((lane >> 4) << 2) + r;
                    float f1 = (rt ? a01[r] : a00[r]) + bf1;
                    float f2 = (rt ? a11[r] : a10[r]) + bf2;
                    *(h16*)(S + OFF_F + p * 768 + SWZ(p, n * 2))         = (h16)tanhf_fast(f1 * f2);
                    *(h16*)(S + OFF_F + p * 768 + SWZ(p, (n + D8n) * 2)) = (h16)tanhf_fast(f1);
                }
            }
        }
    }
    __syncthreads();

    // ---------- phase 4 A-load: f fragments -> regs ----------
    f16x8 Af[2][12];                   // [rowtile][kf], K=384
    {
        int pr = lane & 15, kg = (lane >> 4) << 3;
        #pragma unroll
        for (int rt = 0; rt < 2; ++rt) {
            int p = rt * 16 + pr;
            #pragma unroll
            for (int kf = 0; kf < 12; ++kf) {
                int k0 = kf * 32 + kg;
                Af[rt][kf] = *(const f16x8*)(S + OFF_F + p * 768 + SWZ(p, k0 * 2));
            }
        }
    }
    __syncthreads();   // f dead; g region may now be written

    // ---------- phase 4 compute: g = leaky(f @ l3w1 + b) -> g LDS f16 ----------
    {
        int pr = lane & 15, kg = (lane >> 4) << 3;
        #pragma unroll
        for (int q = 0; q < 3; ++q) {
            int ntb = wv * 12 + q * 4;
            f32x4 acc[4][2];
            #pragma unroll
            for (int nn = 0; nn < 4; ++nn) { acc[nn][0] = (f32x4){0.f,0.f,0.f,0.f}; acc[nn][1] = acc[nn][0]; }
            for (int kf = 0; kf < 12; ++kf) {
                int koff = kf * 32 + kg;
                f16x8 bq[4];
                #pragma unroll
                for (int nn = 0; nn < 4; ++nn)
                    bq[nn] = *(const f16x8*)(W31T + ((ntb + nn) * 16 + pr) * D4n + koff);
                #pragma unroll
                for (int nn = 0; nn < 4; ++nn) {
                    acc[nn][0] = MFMA16(Af[0][kf], bq[nn], acc[nn][0]);
                    acc[nn][1] = MFMA16(Af[1][kf], bq[nn], acc[nn][1]);
                }
            }
            #pragma unroll
            for (int nn = 0; nn < 4; ++nn) {
                int n = (ntb + nn) * 16 + pr;
                float bb = l3b1[n];
                #pragma unroll
                for (int rt = 0; rt < 2; ++rt) {
                    #pragma unroll
                    for (int r = 0; r < 4; ++r) {
                        int p = rt * 16 + ((lane >> 4) << 2) + r;
                        float gv = acc[nn][rt][r] + bb;
                        gv = (gv > 0.f) ? gv : 0.01f * gv;
                        *(h16*)(S + OFF_G + p * 1536 + SWZ(p, n * 2)) = (h16)gv;
                    }
                }
            }
        }
    }
    __syncthreads();

    // ---------- phase 5: w = g @ l3w2 + b, fused slice_mul ----------
    {
        int pr = lane & 15, kg = (lane >> 4) << 3;
        float acc8[2][4];
        #pragma unroll
        for (int rt = 0; rt < 2; ++rt)
            #pragma unroll
            for (int r = 0; r < 4; ++r) acc8[rt][r] = 0.f;
        int cur_oc = (wv * 24) >> 5;

        for (int q = 0; q < 6; ++q) {
            int ntb = wv * 24 + q * 4;
            int oc = ntb >> 5;
            if (oc != cur_oc) {
                // flush acc8 -> red[wv][p][cur_oc]
                #pragma unroll
                for (int rt = 0; rt < 2; ++rt)
                    #pragma unroll
                    for (int r = 0; r < 4; ++r) {
                        float v = acc8[rt][r];
                        v += __shfl_xor(v, 1); v += __shfl_xor(v, 2);
                        v += __shfl_xor(v, 4); v += __shfl_xor(v, 8);
                        if ((lane & 15) == 0) {
                            int p = rt * 16 + ((lane >> 4) << 2) + r;
                            s_red[(wv * 32 + p) * 3 + cur_oc] += v;
                        }
                        acc8[rt][r] = 0.f;
                    }
                cur_oc = oc;
            }
            f32x4 acc[4][2];
            #pragma unroll
            for (int nn = 0; nn < 4; ++nn) { acc[nn][0] = (f32x4){0.f,0.f,0.f,0.f}; acc[nn][1] = acc[nn][0]; }
            for (int kf = 0; kf < 24; ++kf) {
                int koff = kf * 32 + kg;
                f16x8 a0 = *(const f16x8*)(S + OFF_G + pr * 1536 + SWZ(pr, koff * 2));
                int p1 = 16 + pr;
                f16x8 a1 = *(const f16x8*)(S + OFF_G + p1 * 1536 + SWZ(p1, koff * 2));
                f16x8 bq[4];
                #pragma unroll
                for (int nn = 0; nn < 4; ++nn)
                    bq[nn] = *(const f16x8*)(W32T + ((ntb + nn) * 16 + pr) * D2n + koff);
                #pragma unroll
                for (int nn = 0; nn < 4; ++nn) {
                    acc[nn][0] = MFMA16(a0, bq[nn], acc[nn][0]);
                    acc[nn][1] = MFMA16(a1, bq[nn], acc[nn][1]);
                }
            }
            #pragma unroll
            for (int nn = 0; nn < 4; ++nn) {
                int n = (ntb + nn) * 16 + pr;
                float wb = l3b2[n];
                int k  = n & 511;
                int c  = k >> 4, k1 = (k >> 2) & 3, k2 = k & 3;
                const h16* lrr = s_lrr + (c * 4 + k1) * 48;
                #pragma unroll
                for (int rt = 0; rt < 2; ++rt) {
                    #pragma unroll
                    for (int r = 0; r < 4; ++r) {
                        int p = rt * 16 + ((lane >> 4) << 2) + r;
                        float sv = (float)lrr[s_sc[p * 4 + k2]];
                        acc8[rt][r] += (acc[nn][rt][r] + wb) * sv;
                    }
                }
            }
        }
        // final flush
        #pragma unroll
        for (int rt = 0; rt < 2; ++rt)
            #pragma unroll
            for (int r = 0; r < 4; ++r) {
                float v = acc8[rt][r];
                v += __shfl_xor(v, 1); v += __shfl_xor(v, 2);
                v += __shfl_xor(v, 4); v += __shfl_xor(v, 8);
                if ((lane & 15) == 0) {
                    int p = rt * 16 + ((lane >> 4) << 2) + r;
                    s_red[(wv * 32 + p) * 3 + cur_oc] += v;
                }
            }
    }
    __syncthreads();

    // ---------- output ----------
    if (tid < 96) {
        int p = tid / 3, oc = tid % 3;
        float s = s_red[(0 * 32 + p) * 3 + oc] + s_red[(1 * 32 + p) * 3 + oc]
                + s_red[(2 * 32 + p) * 3 + oc] + s_red[(3 * 32 + p) * 3 + oc];
        out[((b * OUTC + oc) * 192 + h) * 192 + (w0 + p)] = tanhf_fast(s);
    }
}

extern "C" void kernel_launch(void* const* d_in, const int* in_sizes, int n_in,
                              void* d_out, int out_size, void* d_ws, size_t ws_size,
                              hipStream_t stream) {
    const float* lr   = (const float*)d_in[0];
    const float* ft_w = (const float*)d_in[4];
    const float* ft_b = (const float*)d_in[5];
    const float* l1w1 = (const float*)d_in[6];
    const float* l1b1 = (const float*)d_in[7];
    const float* l1w2 = (const float*)d_in[8];
    const float* l1b2 = (const float*)d_in[9];
    const float* l2w1 = (const float*)d_in[10];
    const float* l2b1 = (const float*)d_in[11];
    const float* l2w2 = (const float*)d_in[12];
    const float* l2b2 = (const float*)d_in[13];
    const float* l3w1 = (const float*)d_in[14];
    const float* l3b1 = (const float*)d_in[15];
    const float* l3w2 = (const float*)d_in[16];
    const float* l3b2 = (const float*)d_in[17];
    float* outp = (float*)d_out;

    char* ws = (char*)d_ws;
    float* ftmap = (float*)(ws + 0);            // 294912 B
    h16* w12t = (h16*)(ws + 294912);            // 73728 B
    h16* w22t = (h16*)(ws + 368640);            // 73728 B
    h16* w31t = (h16*)(ws + 442368);            // 589824 B
    h16* w32t = (h16*)(ws + 1032192);           // 2359296 B -> total 3391488 B

    hipLaunchKernelGGL(prep_kernel, dim3(1512), dim3(256), 0, stream,
                       l1w2, l2w2, l3w1, l3w2, w12t, w22t, w31t, w32t);
    hipLaunchKernelGGL(ft_kernel, dim3(288), dim3(256), 0, stream, lr, ft_w, ft_b, ftmap);
    hipLaunchKernelGGL(fused_kernel, dim3(2304), dim3(256), 0, stream,
                       lr, ftmap,
                       l1w1, l1b1, l2w1, l2b1,
                       l1b2, l2b2, l3b1, l3b2,
                       w12t, w22t, w31t, w32t,
                       outp);
}

// Round 3
// 692.819 us; speedup vs baseline: 17.1775x; 1.2539x over previous
//
#include <hip/hip_runtime.h>
#include <math.h>

#define H_IN   48
#define W_IN   48
#define INC    32
#define OUTC   3
#define FT     16
#define Dn     1536
#define D8n    192
#define D4n    384
#define D2n    768

typedef _Float16 h16;
typedef _Float16 f16x8 __attribute__((ext_vector_type(8)));
typedef _Float16 f16x4 __attribute__((ext_vector_type(4)));
typedef float    f32x4 __attribute__((ext_vector_type(4)));

#define MFMA16(a, b, c) __builtin_amdgcn_mfma_f32_16x16x32_f16((a), (b), (c), 0, 0, 0)

__device__ __forceinline__ int reflect48(int i) {
    return (i < 0) ? -i : ((i > 47) ? 94 - i : i);
}

__device__ __forceinline__ float tanhf_fast(float x) {
    float e = __expf(2.f * x);
    return 1.f - 2.f / (e + 1.f);
}

// row-XOR swizzle: byte column ^ ((row&7)<<4)
#define SWZ(p, bc) ((bc) ^ (((p) & 7) << 4))

// ---------------- feature_trans conv ----------------
__global__ __launch_bounds__(256) void ft_kernel(const float* __restrict__ lr,
                                                 const float* __restrict__ ft_w,
                                                 const float* __restrict__ ft_b,
                                                 float* __restrict__ ftmap) {
    int idx = blockIdx.x * 256 + threadIdx.x;
    if (idx >= 2 * FT * H_IN * W_IN) return;
    int x = idx % W_IN;
    int y = (idx / W_IN) % H_IN;
    int o = (idx / (W_IN * H_IN)) % FT;
    int bb = idx / (W_IN * H_IN * FT);
    float acc = ft_b[o];
    for (int c = 0; c < INC; ++c) {
        const float* lrc = lr + ((bb * INC + c) * H_IN) * W_IN;
        const float* wc  = ft_w + ((o * INC + c) * 4) * 4;
        #pragma unroll
        for (int dy = 0; dy < 4; ++dy) {
            int ry = reflect48(y + dy - 1);
            #pragma unroll
            for (int dx = 0; dx < 4; ++dx) {
                int rx = reflect48(x + dx - 1);
                acc += lrc[ry * W_IN + rx] * wc[dy * 4 + dx];
            }
        }
    }
    ftmap[idx] = acc;
}

// ---------------- weight transpose + f32->f16 ----------------
__global__ __launch_bounds__(256) void prep_kernel(const float* __restrict__ l1w2,
                                                   const float* __restrict__ l2w2,
                                                   const float* __restrict__ l3w1,
                                                   const float* __restrict__ l3w2,
                                                   h16* __restrict__ w12t, h16* __restrict__ w22t,
                                                   h16* __restrict__ w31t, h16* __restrict__ w32t) {
    __shared__ float tile[32][33];
    int bid = blockIdx.x;
    const float* src; h16* dst; int K, N, t0;
    if (bid < 36)      { src = l1w2; dst = w12t; K = 192; N = 192;  t0 = 0; }
    else if (bid < 72) { src = l2w2; dst = w22t; K = 192; N = 192;  t0 = 36; }
    else if (bid < 360){ src = l3w1; dst = w31t; K = 384; N = 768;  t0 = 72; }
    else               { src = l3w2; dst = w32t; K = 768; N = 1536; t0 = 360; }
    int t = bid - t0;
    int ntx = N >> 5;
    int kt = t / ntx, nt = t - kt * ntx;
    int k0 = kt << 5, n0 = nt << 5;
    int tx = threadIdx.x & 31, ty = threadIdx.x >> 5;
    #pragma unroll
    for (int i = 0; i < 4; ++i)
        tile[ty + i * 8][tx] = src[(k0 + ty + i * 8) * N + n0 + tx];
    __syncthreads();
    #pragma unroll
    for (int i = 0; i < 4; ++i)
        dst[(n0 + ty + i * 8) * K + k0 + tx] = (h16)tile[tx][ty + i * 8];
}

// =================================================================
// Kernel A: phases 0-4 (MLP up to g), 32 pixels/block, writes g-frags
// LDS: h1[0,12288) h2[12288,24576) osf[24576,27136) ; f aliases [0,24576);
//      g aliases [0,49152)
// =================================================================
#define A_OFF_H1   0
#define A_OFF_H2   12288
#define A_OFF_OSF  24576
#define A_OFF_F    0
#define A_OFF_G    0
#define A_S_BYTES  49152

__global__ __launch_bounds__(256, 3) void fused_a(
    const float* __restrict__ ftmap,
    const float* __restrict__ l1w1, const float* __restrict__ l1b1,
    const float* __restrict__ l2w1, const float* __restrict__ l2b1,
    const float* __restrict__ l1b2, const float* __restrict__ l2b2,
    const float* __restrict__ l3b1,
    const h16* __restrict__ W12T, const h16* __restrict__ W22T,
    const h16* __restrict__ W31T,
    h16* __restrict__ Gf)
{
    __shared__ __align__(16) char S[A_S_BYTES];

    const int tid  = threadIdx.x;
    const int lane = tid & 63;
    const int wv   = tid >> 6;
    const int bid  = blockIdx.x;
    const int b    = bid / 1152;
    const int rem  = bid % 1152;
    const int h    = rem / 6;
    const int w0   = (rem % 6) * 32;

    const float ch = (h + 1) * 0.25f - 0.625f;
    const int   fh = (int)floorf(ch);
    const float offh = (float)fh - ch;
    const int   rfh = reflect48(fh);

    float* s_osf = (float*)(S + A_OFF_OSF);

    // ---------- phase 0: osf ----------
    if (tid < 32) {
        int w = w0 + tid;
        float cw = (w + 1) * 0.25f - 0.625f;
        int fw = (int)floorf(cw);
        float* o = s_osf + tid * 20;
        o[16] = offh; o[17] = (float)fw - cw; o[18] = 4.f; o[19] = 4.f;
    }
    {   // srf gather: 32p x 16ch
        int p = tid >> 3;
        int c0 = (tid & 7) * 2;
        int w = w0 + p;
        float cw = (w + 1) * 0.25f - 0.625f;
        int rfw = reflect48((int)floorf(cw));
        float* o = s_osf + p * 20;
        o[c0]     = ftmap[((b * FT + c0) * H_IN + rfh) * W_IN + rfw];
        o[c0 + 1] = ftmap[((b * FT + c0 + 1) * H_IN + rfh) * W_IN + rfw];
    }
    __syncthreads();

    // ---------- phase 1: h{1,2} = tanh(osf @ l{1,2}w1 + b) ----------
    for (int idx = tid; idx < 2 * 32 * D8n; idx += 256) {
        int br = idx / 6144;
        int r2 = idx - br * 6144;
        int p  = r2 / D8n;
        int j  = r2 - p * D8n;
        const float* W = br ? l2w1 : l1w1;
        const float* B = br ? l2b1 : l1b1;
        const float* o = s_osf + p * 20;
        float acc = B[j];
        #pragma unroll
        for (int i = 0; i < 20; ++i) acc += o[i] * W[i * D8n + j];
        int base = br ? A_OFF_H2 : A_OFF_H1;
        *(h16*)(S + base + p * 384 + SWZ(p, j * 2)) = (h16)tanhf_fast(acc);
    }
    __syncthreads();

    // ---------- phase 2 A-load ----------
    f16x8 Ah[2][2][6];
    {
        int pr = lane & 15, kg = (lane >> 4) << 3;
        #pragma unroll
        for (int br = 0; br < 2; ++br)
            #pragma unroll
            for (int rt = 0; rt < 2; ++rt) {
                int p = rt * 16 + pr;
                #pragma unroll
                for (int kf = 0; kf < 6; ++kf) {
                    int k0 = kf * 32 + kg;
                    Ah[br][rt][kf] = *(const f16x8*)(S + (br ? A_OFF_H2 : A_OFF_H1) + p * 384 + SWZ(p, k0 * 2));
                }
            }
    }
    __syncthreads();

    // ---------- phase 2 compute + merge -> f ----------
    {
        int pr = lane & 15, kg = (lane >> 4) << 3;
        #pragma unroll
        for (int cc = 0; cc < 3; ++cc) {
            int c = wv * 3 + cc;
            int n = c * 16 + pr;
            f32x4 a00 = {0.f,0.f,0.f,0.f}, a01 = a00, a10 = a00, a11 = a00;
            #pragma unroll
            for (int kf = 0; kf < 6; ++kf) {
                int koff = kf * 32 + kg;
                f16x8 b0 = *(const f16x8*)(W12T + n * D8n + koff);
                f16x8 b1 = *(const f16x8*)(W22T + n * D8n + koff);
                a00 = MFMA16(Ah[0][0][kf], b0, a00);
                a01 = MFMA16(Ah[0][1][kf], b0, a01);
                a10 = MFMA16(Ah[1][0][kf], b1, a10);
                a11 = MFMA16(Ah[1][1][kf], b1, a11);
            }
            float bf1 = l1b2[n], bf2 = l2b2[n];
            #pragma unroll
            for (int rt = 0; rt < 2; ++rt) {
                #pragma unroll
                for (int r = 0; r < 4; ++r) {
                    int p = rt * 16 + ((lane >> 4) << 2) + r;
                    float f1 = (rt ? a01[r] : a00[r]) + bf1;
                    float f2 = (rt ? a11[r] : a10[r]) + bf2;
                    *(h16*)(S + A_OFF_F + p * 768 + SWZ(p, n * 2))         = (h16)tanhf_fast(f1 * f2);
                    *(h16*)(S + A_OFF_F + p * 768 + SWZ(p, (n + D8n) * 2)) = (h16)tanhf_fast(f1);
                }
            }
        }
    }
    __syncthreads();

    // ---------- phase 4 A-load ----------
    f16x8 Af[2][12];
    {
        int pr = lane & 15, kg = (lane >> 4) << 3;
        #pragma unroll
        for (int rt = 0; rt < 2; ++rt) {
            int p = rt * 16 + pr;
            #pragma unroll
            for (int kf = 0; kf < 12; ++kf) {
                int k0 = kf * 32 + kg;
                Af[rt][kf] = *(const f16x8*)(S + A_OFF_F + p * 768 + SWZ(p, k0 * 2));
            }
        }
    }
    __syncthreads();

    // ---------- phase 4 compute: g = leaky(f @ l3w1 + b) -> g LDS ----------
    {
        int pr = lane & 15, kg = (lane >> 4) << 3;
        #pragma unroll
        for (int q = 0; q < 3; ++q) {
            int ntb = wv * 12 + q * 4;
            f32x4 acc[4][2];
            #pragma unroll
            for (int nn = 0; nn < 4; ++nn) { acc[nn][0] = (f32x4){0.f,0.f,0.f,0.f}; acc[nn][1] = acc[nn][0]; }
            for (int kf = 0; kf < 12; ++kf) {
                int koff = kf * 32 + kg;
                f16x8 bq[4];
                #pragma unroll
                for (int nn = 0; nn < 4; ++nn)
                    bq[nn] = *(const f16x8*)(W31T + ((ntb + nn) * 16 + pr) * D4n + koff);
                #pragma unroll
                for (int nn = 0; nn < 4; ++nn) {
                    acc[nn][0] = MFMA16(Af[0][kf], bq[nn], acc[nn][0]);
                    acc[nn][1] = MFMA16(Af[1][kf], bq[nn], acc[nn][1]);
                }
            }
            #pragma unroll
            for (int nn = 0; nn < 4; ++nn) {
                int n = (ntb + nn) * 16 + pr;
                float bb = l3b1[n];
                #pragma unroll
                for (int rt = 0; rt < 2; ++rt) {
                    #pragma unroll
                    for (int r = 0; r < 4; ++r) {
                        int p = rt * 16 + ((lane >> 4) << 2) + r;
                        float gv = acc[nn][rt][r] + bb;
                        gv = (gv > 0.f) ? gv : 0.01f * gv;
                        *(h16*)(S + A_OFF_G + p * 1536 + SWZ(p, n * 2)) = (h16)gv;
                    }
                }
            }
        }
    }
    __syncthreads();

    // ---------- phase 5': export g as MFMA B-fragments, coalesced ----------
    {
        int pr = lane & 15, kg = lane >> 4;
        int ptg0 = (b * 192 + h) * 12 + (w0 >> 4);
        #pragma unroll
        for (int i = 0; i < 12; ++i) {
            int pair = wv * 12 + i;           // 0..47
            int rt = pair / 24, kf = pair % 24;
            int p = rt * 16 + pr;
            f16x8 v = *(const f16x8*)(S + A_OFF_G + p * 1536 + SWZ(p, (kf * 32 + kg * 8) * 2));
            size_t e = ((size_t)((ptg0 + rt) * 24 + kf) * 4 + kg) * 16 + pr;
            *(f16x8*)(Gf + e * 8) = v;
        }
    }
}

// =================================================================
// Kernel B: w = g @ W32T (+b) fused with sel-mul + reduce + tanh
// 64 pixels/block, 512 threads (8 waves), orientation-swapped MFMA:
// C row = n (4 consecutive per lane), C col = pixel.
// =================================================================
#define B_S_BYTES (65536 + 6144)

__global__ __launch_bounds__(512, 4) void gemm_b(
    const float* __restrict__ lr,
    const h16* __restrict__ Gf,
    const h16* __restrict__ W32T,
    const float* __restrict__ l3b2,
    float* __restrict__ out)
{
    __shared__ __align__(16) char S[B_S_BYTES];
    float* s_red = (float*)(S + 65536);       // [8 waves][64 p][3 oc]

    const int tid  = threadIdx.x;
    const int lane = tid & 63;
    const int wvv  = tid >> 6;                // 0..7
    const int pr   = lane & 15;
    const int kg   = lane >> 4;               // 0..3

    const int bid = blockIdx.x;
    const int b   = bid / 576;
    const int rem = bid % 576;
    const int h   = rem / 3;
    const int w0  = (rem % 3) * 64;

    const float chh = (h + 1) * 0.25f - 0.625f;
    const int fh = (int)floorf(chh);

    // ---------- sel prefill: s_sel[p][k] = lr[b][c][rh(k1)][rw(p,k2)], swizzled ----------
    {
        int k = tid;                          // 0..511
        int c = k >> 4, k1 = (k >> 2) & 3, k2 = k & 3;
        int rh = reflect48(fh - 1 + k1);
        const float* lrrow = lr + ((b * INC + c) * H_IN + rh) * W_IN;
        #pragma unroll 8
        for (int p = 0; p < 64; ++p) {
            float cw = (w0 + p + 1) * 0.25f - 0.625f;
            int fw = (int)floorf(cw);
            float v = lrrow[reflect48(fw - 1 + k2)];
            *(h16*)(S + p * 1024 + ((k * 2) ^ ((p & 7) << 4))) = (h16)v;
        }
    }
    __syncthreads();

    const int ptB = (b * 192 + h) * 12 + (w0 >> 4);
    const int nt0 = wvv * 12;

    float acc0[4], acc1[4], acc2[4];
    #pragma unroll
    for (int pt = 0; pt < 4; ++pt) { acc0[pt] = 0.f; acc1[pt] = 0.f; acc2[pt] = 0.f; }

    const h16* Gbase = Gf + ((size_t)(kg * 16 + pr)) * 8;

    for (int cc2 = 0; cc2 < 12; ++cc2) {      // K chunks of 64
        // load g B-fragments for this chunk (coalesced, L2-hot)
        f16x8 gB[4][2];
        #pragma unroll
        for (int pt = 0; pt < 4; ++pt)
            #pragma unroll
            for (int kf = 0; kf < 2; ++kf)
                gB[pt][kf] = *(const f16x8*)(Gbase + ((size_t)((ptB + pt) * 24 + (cc2 * 2 + kf)) * 64) * 8);

        for (int i = 0; i < 12; ++i) {
            int nt = nt0 + i;
            int oc = nt >> 5;                  // wave-uniform
            int kbase = (nt & 31) * 16 + kg * 4;

            const h16* wrow = W32T + (size_t)(nt * 16 + pr) * D2n + cc2 * 64 + kg * 8;
            f16x8 Wa0 = *(const f16x8*)(wrow);
            f16x8 Wa1 = *(const f16x8*)(wrow + 32);

            f32x4 wacc[4];
            #pragma unroll
            for (int pt = 0; pt < 4; ++pt) {
                wacc[pt] = (f32x4){0.f,0.f,0.f,0.f};
                wacc[pt] = MFMA16(Wa0, gB[pt][0], wacc[pt]);
                wacc[pt] = MFMA16(Wa1, gB[pt][1], wacc[pt]);
            }

            float4 b2v;
            if (cc2 == 0) b2v = *(const float4*)(l3b2 + nt * 16 + kg * 4);

            if (oc == 0) {
                #pragma unroll
                for (int pt = 0; pt < 4; ++pt) {
                    int p = pt * 16 + pr;
                    f16x4 sl = *(const f16x4*)(S + p * 1024 + ((kbase * 2) ^ ((p & 7) << 4)));
                    #pragma unroll
                    for (int r = 0; r < 4; ++r) {
                        float sv = (float)sl[r];
                        acc0[pt] += wacc[pt][r] * sv;
                        if (cc2 == 0) acc0[pt] += ((const float*)&b2v)[r] * sv;
                    }
                }
            } else if (oc == 1) {
                #pragma unroll
                for (int pt = 0; pt < 4; ++pt) {
                    int p = pt * 16 + pr;
                    f16x4 sl = *(const f16x4*)(S + p * 1024 + ((kbase * 2) ^ ((p & 7) << 4)));
                    #pragma unroll
                    for (int r = 0; r < 4; ++r) {
                        float sv = (float)sl[r];
                        acc1[pt] += wacc[pt][r] * sv;
                        if (cc2 == 0) acc1[pt] += ((const float*)&b2v)[r] * sv;
                    }
                }
            } else {
                #pragma unroll
                for (int pt = 0; pt < 4; ++pt) {
                    int p = pt * 16 + pr;
                    f16x4 sl = *(const f16x4*)(S + p * 1024 + ((kbase * 2) ^ ((p & 7) << 4)));
                    #pragma unroll
                    for (int r = 0; r < 4; ++r) {
                        float sv = (float)sl[r];
                        acc2[pt] += wacc[pt][r] * sv;
                        if (cc2 == 0) acc2[pt] += ((const float*)&b2v)[r] * sv;
                    }
                }
            }
        }
    }

    // ---------- cross-lane + cross-wave reduction ----------
    #pragma unroll
    for (int pt = 0; pt < 4; ++pt) {
        float v0 = acc0[pt], v1 = acc1[pt], v2 = acc2[pt];
        v0 += __shfl_xor(v0, 16); v0 += __shfl_xor(v0, 32);
        v1 += __shfl_xor(v1, 16); v1 += __shfl_xor(v1, 32);
        v2 += __shfl_xor(v2, 16); v2 += __shfl_xor(v2, 32);
        if (lane < 16) {
            float* r = s_red + ((size_t)wvv * 64 + pt * 16 + pr) * 3;
            r[0] = v0; r[1] = v1; r[2] = v2;
        }
    }
    __syncthreads();
    if (tid < 192) {
        int p = tid / 3, oc = tid % 3;
        float s = 0.f;
        #pragma unroll
        for (int wv2 = 0; wv2 < 8; ++wv2) s += s_red[((size_t)wv2 * 64 + p) * 3 + oc];
        out[((b * OUTC + oc) * 192 + h) * 192 + (w0 + p)] = tanhf_fast(s);
    }
}

// =================================================================
// Fallback (round-2 single fused kernel) if ws too small
// =================================================================
__global__ __launch_bounds__(256, 2) void fused_fallback(
    const float* __restrict__ lr, const float* __restrict__ ftmap,
    const float* __restrict__ l1w1, const float* __restrict__ l1b1,
    const float* __restrict__ l2w1, const float* __restrict__ l2b1,
    const float* __restrict__ l1b2, const float* __restrict__ l2b2,
    const float* __restrict__ l3b1, const float* __restrict__ l3b2,
    const h16* __restrict__ W12T, const h16* __restrict__ W22T,
    const h16* __restrict__ W31T, const h16* __restrict__ W32T,
    float* __restrict__ out)
{
    __shared__ __align__(16) char S[63104];
    const int tid  = threadIdx.x;
    const int lane = tid & 63;
    const int wv   = tid >> 6;
    const int bid  = blockIdx.x;
    const int b    = bid / 1152;
    const int rem  = bid % 1152;
    const int h    = rem / 6;
    const int w0   = (rem % 6) * 32;

    const float ch = (h + 1) * 0.25f - 0.625f;
    const int   fh = (int)floorf(ch);
    const float offh = (float)fh - ch;
    const int   rfh = reflect48(fh);

    float* s_osf = (float*)(S + 24576);
    unsigned char* s_sc = (unsigned char*)(S + 61440);
    h16*   s_lrr = (h16*)(S + 49152);
    float* s_red = (float*)(S + 61568);

    if (tid < 128) {
        int p = tid >> 2, k2 = tid & 3;
        int w = w0 + p;
        float cw = (w + 1) * 0.25f - 0.625f;
        int fw = (int)floorf(cw);
        s_sc[p * 4 + k2] = (unsigned char)reflect48(fw - 1 + k2);
        if (k2 == 0) {
            float* o = s_osf + p * 20;
            o[16] = offh; o[17] = (float)fw - cw; o[18] = 4.f; o[19] = 4.f;
        }
    }
    {
        int p = tid >> 3;
        int c0 = (tid & 7) * 2;
        int w = w0 + p;
        float cw = (w + 1) * 0.25f - 0.625f;
        int rfw = reflect48((int)floorf(cw));
        float* o = s_osf + p * 20;
        o[c0]     = ftmap[((b * FT + c0) * H_IN + rfh) * W_IN + rfw];
        o[c0 + 1] = ftmap[((b * FT + c0 + 1) * H_IN + rfh) * W_IN + rfw];
    }
    for (int idx = tid; idx < 32 * 4 * 48; idx += 256) {
        int c = idx / 192, r2 = idx - c * 192, k1 = r2 / 48, col = r2 - k1 * 48;
        int row = reflect48(fh - 1 + k1);
        s_lrr[idx] = (h16)lr[((b * INC + c) * H_IN + row) * W_IN + col];
    }
    for (int idx = tid; idx < 4 * 32 * 3; idx += 256) s_red[idx] = 0.f;
    __syncthreads();

    for (int idx = tid; idx < 2 * 32 * D8n; idx += 256) {
        int br = idx / 6144;
        int r2 = idx - br * 6144;
        int p  = r2 / D8n;
        int j  = r2 - p * D8n;
        const float* W = br ? l2w1 : l1w1;
        const float* B = br ? l2b1 : l1b1;
        const float* o = s_osf + p * 20;
        float acc = B[j];
        #pragma unroll
        for (int i = 0; i < 20; ++i) acc += o[i] * W[i * D8n + j];
        int base = br ? 12288 : 0;
        *(h16*)(S + base + p * 384 + SWZ(p, j * 2)) = (h16)tanhf_fast(acc);
    }
    __syncthreads();

    f16x8 Ah[2][2][6];
    {
        int pr = lane & 15, kg = (lane >> 4) << 3;
        #pragma unroll
        for (int br = 0; br < 2; ++br)
            #pragma unroll
            for (int rt = 0; rt < 2; ++rt) {
                int p = rt * 16 + pr;
                #pragma unroll
                for (int kf = 0; kf < 6; ++kf)
                    Ah[br][rt][kf] = *(const f16x8*)(S + (br ? 12288 : 0) + p * 384 + SWZ(p, (kf * 32 + kg) * 2));
            }
    }
    __syncthreads();

    {
        int pr = lane & 15, kg = (lane >> 4) << 3;
        #pragma unroll
        for (int cc = 0; cc < 3; ++cc) {
            int c = wv * 3 + cc;
            int n = c * 16 + pr;
            f32x4 a00 = {0.f,0.f,0.f,0.f}, a01 = a00, a10 = a00, a11 = a00;
            #pragma unroll
            for (int kf = 0; kf < 6; ++kf) {
                int koff = kf * 32 + kg;
                f16x8 b0 = *(const f16x8*)(W12T + n * D8n + koff);
                f16x8 b1 = *(const f16x8*)(W22T + n * D8n + koff);
                a00 = MFMA16(Ah[0][0][kf], b0, a00);
                a01 = MFMA16(Ah[0][1][kf], b0, a01);
                a10 = MFMA16(Ah[1][0][kf], b1, a10);
                a11 = MFMA16(Ah[1][1][kf], b1, a11);
            }
            float bf1 = l1b2[n], bf2 = l2b2[n];
            #pragma unroll
            for (int rt = 0; rt < 2; ++rt)
                #pragma unroll
                for (int r = 0; r < 4; ++r) {
                    int p = rt * 16 + ((lane >> 4) << 2) + r;
                    float f1 = (rt ? a01[r] : a00[r]) + bf1;
                    float f2 = (rt ? a11[r] : a10[r]) + bf2;
                    *(h16*)(S + p * 768 + SWZ(p, n * 2))         = (h16)tanhf_fast(f1 * f2);
                    *(h16*)(S + p * 768 + SWZ(p, (n + D8n) * 2)) = (h16)tanhf_fast(f1);
                }
        }
    }
    __syncthreads();

    f16x8 Af[2][12];
    {
        int pr = lane & 15, kg = (lane >> 4) << 3;
        #pragma unroll
        for (int rt = 0; rt < 2; ++rt) {
            int p = rt * 16 + pr;
            #pragma unroll
            for (int kf = 0; kf < 12; ++kf)
                Af[rt][kf] = *(const f16x8*)(S + p * 768 + SWZ(p, (kf * 32 + kg) * 2));
        }
    }
    __syncthreads();

    {
        int pr = lane & 15, kg = (lane >> 4) << 3;
        #pragma unroll
        for (int q = 0; q < 3; ++q) {
            int ntb = wv * 12 + q * 4;
            f32x4 acc[4][2];
            #pragma unroll
            for (int nn = 0; nn < 4; ++nn) { acc[nn][0] = (f32x4){0.f,0.f,0.f,0.f}; acc[nn][1] = acc[nn][0]; }
            for (int kf = 0; kf < 12; ++kf) {
                int koff = kf * 32 + kg;
                f16x8 bq[4];
                #pragma unroll
                for (int nn = 0; nn < 4; ++nn)
                    bq[nn] = *(const f16x8*)(W31T + ((ntb + nn) * 16 + pr) * D4n + koff);
                #pragma unroll
                for (int nn = 0; nn < 4; ++nn) {
                    acc[nn][0] = MFMA16(Af[0][kf], bq[nn], acc[nn][0]);
                    acc[nn][1] = MFMA16(Af[1][kf], bq[nn], acc[nn][1]);
                }
            }
            #pragma unroll
            for (int nn = 0; nn < 4; ++nn) {
                int n = (ntb + nn) * 16 + pr;
                float bb = l3b1[n];
                #pragma unroll
                for (int rt = 0; rt < 2; ++rt)
                    #pragma unroll
                    for (int r = 0; r < 4; ++r) {
                        int p = rt * 16 + ((lane >> 4) << 2) + r;
                        float gv = acc[nn][rt][r] + bb;
                        gv = (gv > 0.f) ? gv : 0.01f * gv;
                        *(h16*)(S + p * 1536 + SWZ(p, n * 2)) = (h16)gv;
                    }
            }
        }
    }
    __syncthreads();

    {
        int pr = lane & 15, kg = (lane >> 4) << 3;
        float acc8[2][4];
        #pragma unroll
        for (int rt = 0; rt < 2; ++rt)
            #pragma unroll
            for (int r = 0; r < 4; ++r) acc8[rt][r] = 0.f;
        int cur_oc = (wv * 24) >> 5;

        for (int q = 0; q < 6; ++q) {
            int ntb = wv * 24 + q * 4;
            int oc = ntb >> 5;
            if (oc != cur_oc) {
                #pragma unroll
                for (int rt = 0; rt < 2; ++rt)
                    #pragma unroll
                    for (int r = 0; r < 4; ++r) {
                        float v = acc8[rt][r];
                        v += __shfl_xor(v, 1); v += __shfl_xor(v, 2);
                        v += __shfl_xor(v, 4); v += __shfl_xor(v, 8);
                        if ((lane & 15) == 0) {
                            int p = rt * 16 + ((lane >> 4) << 2) + r;
                            s_red[(wv * 32 + p) * 3 + cur_oc] += v;
                        }
                        acc8[rt][r] = 0.f;
                    }
                cur_oc = oc;
            }
            f32x4 acc[4][2];
            #pragma unroll
            for (int nn = 0; nn < 4; ++nn) { acc[nn][0] = (f32x4){0.f,0.f,0.f,0.f}; acc[nn][1] = acc[nn][0]; }
            for (int kf = 0; kf < 24; ++kf) {
                int koff = kf * 32 + kg;
                f16x8 a0 = *(const f16x8*)(S + pr * 1536 + SWZ(pr, koff * 2));
                int p1 = 16 + pr;
                f16x8 a1 = *(const f16x8*)(S + p1 * 1536 + SWZ(p1, koff * 2));
                f16x8 bq[4];
                #pragma unroll
                for (int nn = 0; nn < 4; ++nn)
                    bq[nn] = *(const f16x8*)(W32T + ((ntb + nn) * 16 + pr) * D2n + koff);
                #pragma unroll
                for (int nn = 0; nn < 4; ++nn) {
                    acc[nn][0] = MFMA16(a0, bq[nn], acc[nn][0]);
                    acc[nn][1] = MFMA16(a1, bq[nn], acc[nn][1]);
                }
            }
            #pragma unroll
            for (int nn = 0; nn < 4; ++nn) {
                int n = (ntb + nn) * 16 + pr;
                float wb = l3b2[n];
                int k  = n & 511;
                int c  = k >> 4, k1 = (k >> 2) & 3, k2 = k & 3;
                const h16* lrr = s_lrr + (c * 4 + k1) * 48;
                #pragma unroll
                for (int rt = 0; rt < 2; ++rt)
                    #pragma unroll
                    for (int r = 0; r < 4; ++r) {
                        int p = rt * 16 + ((lane >> 4) << 2) + r;
                        float sv = (float)lrr[s_sc[p * 4 + k2]];
                        acc8[rt][r] += (acc[nn][rt][r] + wb) * sv;
                    }
            }
        }
        #pragma unroll
        for (int rt = 0; rt < 2; ++rt)
            #pragma unroll
            for (int r = 0; r < 4; ++r) {
                float v = acc8[rt][r];
                v += __shfl_xor(v, 1); v += __shfl_xor(v, 2);
                v += __shfl_xor(v, 4); v += __shfl_xor(v, 8);
                if ((lane & 15) == 0) {
                    int p = rt * 16 + ((lane >> 4) << 2) + r;
                    s_red[(wv * 32 + p) * 3 + cur_oc] += v;
                }
            }
    }
    __syncthreads();

    if (tid < 96) {
        int p = tid / 3, oc = tid % 3;
        float s = s_red[(0 * 32 + p) * 3 + oc] + s_red[(1 * 32 + p) * 3 + oc]
                + s_red[(2 * 32 + p) * 3 + oc] + s_red[(3 * 32 + p) * 3 + oc];
        out[((b * OUTC + oc) * 192 + h) * 192 + (w0 + p)] = tanhf_fast(s);
    }
}

extern "C" void kernel_launch(void* const* d_in, const int* in_sizes, int n_in,
                              void* d_out, int out_size, void* d_ws, size_t ws_size,
                              hipStream_t stream) {
    const float* lr   = (const float*)d_in[0];
    const float* ft_w = (const float*)d_in[4];
    const float* ft_b = (const float*)d_in[5];
    const float* l1w1 = (const float*)d_in[6];
    const float* l1b1 = (const float*)d_in[7];
    const float* l1w2 = (const float*)d_in[8];
    const float* l1b2 = (const float*)d_in[9];
    const float* l2w1 = (const float*)d_in[10];
    const float* l2b1 = (const float*)d_in[11];
    const float* l2w2 = (const float*)d_in[12];
    const float* l2b2 = (const float*)d_in[13];
    const float* l3w1 = (const float*)d_in[14];
    const float* l3b1 = (const float*)d_in[15];
    const float* l3w2 = (const float*)d_in[16];
    const float* l3b2 = (const float*)d_in[17];
    float* outp = (float*)d_out;

    char* ws = (char*)d_ws;
    float* ftmap = (float*)(ws + 0);            // 294912 B
    h16* w12t = (h16*)(ws + 294912);
    h16* w22t = (h16*)(ws + 368640);
    h16* w31t = (h16*)(ws + 442368);
    h16* w32t = (h16*)(ws + 1032192);           // ends 3391488
    h16* Gf   = (h16*)(ws + 3391488);           // 113246208 B -> total 116637696

    hipLaunchKernelGGL(prep_kernel, dim3(1512), dim3(256), 0, stream,
                       l1w2, l2w2, l3w1, l3w2, w12t, w22t, w31t, w32t);
    hipLaunchKernelGGL(ft_kernel, dim3(288), dim3(256), 0, stream, lr, ft_w, ft_b, ftmap);

    if (ws_size >= (size_t)116637696) {
        hipLaunchKernelGGL(fused_a, dim3(2304), dim3(256), 0, stream,
                           ftmap, l1w1, l1b1, l2w1, l2b1,
                           l1b2, l2b2, l3b1,
                           w12t, w22t, w31t, Gf);
        hipLaunchKernelGGL(gemm_b, dim3(1152), dim3(512), 0, stream,
                           lr, Gf, w32t, l3b2, outp);
    } else {
        hipLaunchKernelGGL(fused_fallback, dim3(2304), dim3(256), 0, stream,
                           lr, ftmap,
                           l1w1, l1b1, l2w1, l2b1,
                           l1b2, l2b2, l3b1, l3b2,
                           w12t, w22t, w31t, w32t,
                           outp);
    }
}